// Round 5
// baseline (132.487 us; speedup 1.0000x reference)
//
#include <hip/hip_runtime.h>

#define K_TAPS 9
#define CC 64
#define HH 256
#define WW 256
#define BB 4
#define NN 16384
#define NPTS (BB * NN)
#define SCLX (2.0f / 255.0f)
#define SCLY (2.0f / 255.0f)
#define PRM_STRIDE 32

__device__ __forceinline__ float softplus_f(float x) {
    return fmaxf(x, 0.0f) + log1pf(expf(-fabsf(x)));
}
__device__ __forceinline__ float leaky_f(float x) { return x >= 0.0f ? x : 0.2f * x; }
__device__ __forceinline__ float clampf(float x, float lo, float hi) {
    return fminf(fmaxf(x, lo), hi);
}

// transpose (B, C, H*W) -> (B, H*W, C)
__global__ void __launch_bounds__(256) transpose_kernel(const float* __restrict__ feat,
                                                        float* __restrict__ featT) {
    __shared__ float tile[64][65];
    int b = blockIdx.y;
    int p0 = blockIdx.x * 64;
    int tp = threadIdx.x & 63;
    int tq = threadIdx.x >> 6;
    const float* fb = feat + (size_t)b * CC * HH * WW;
#pragma unroll
    for (int i = 0; i < 16; ++i) {
        int c = tq * 16 + i;
        tile[c][tp] = fb[(size_t)c * (HH * WW) + p0 + tp];
    }
    __syncthreads();
    float* ob = featT + ((size_t)b * (HH * WW) + p0) * CC;
#pragma unroll
    for (int i = 0; i < 16; ++i) {
        int p = tq * 16 + i;
        ob[(size_t)p * CC + tp] = tile[tp][p];
    }
}

// bilinear sample of 4 channels (one float4) at grid coords (gx,gy) in [-1,1]
__device__ __forceinline__ float4 bilin4(const float4* __restrict__ base, float gx, float gy,
                                         int c4) {
    float ix = clampf((gx + 1.0f) * 0.5f * 255.0f, 0.0f, 255.0f);
    float iy = clampf((gy + 1.0f) * 0.5f * 255.0f, 0.0f, 255.0f);
    float x0f = floorf(ix), y0f = floorf(iy);
    float wx = ix - x0f, wy = iy - y0f;
    int x0 = (int)x0f, y0 = (int)y0f;
    int x1 = min(x0 + 1, 255), y1 = min(y0 + 1, 255);
    float4 f00 = base[((y0 << 8) + x0) * 16 + c4];
    float4 f01 = base[((y0 << 8) + x1) * 16 + c4];
    float4 f10 = base[((y1 << 8) + x0) * 16 + c4];
    float4 f11 = base[((y1 << 8) + x1) * 16 + c4];
    float omx = 1.0f - wx, omy = 1.0f - wy;
    float4 v;
    v.x = (f00.x * omx + f01.x * wx) * omy + (f10.x * omx + f11.x * wx) * wy;
    v.y = (f00.y * omx + f01.y * wx) * omy + (f10.y * omx + f11.y * wx) * wy;
    v.z = (f00.z * omx + f01.z * wx) * omy + (f10.z * omx + f11.z * wx) * wy;
    v.w = (f00.w * omx + f01.w * wx) * omy + (f10.w * omx + f11.w * wx) * wy;
    return v;
}

// ---------------- K2: register-blocked MLP, 128 points/block, 4x8 tile/thread ----------------
// act LDS layout: row stride 128 floats (32 float4 slots), float4-slot XOR swizzle:
//   logical chunk c4 of row r lives at physical slot (c4 ^ (r & 7)).
// Phase-A stores and GEMM reads are row-uniform per instr -> conflict-free;
// inter-layer float4 writes spread to 2 lanes/bank (free).
__global__ void __launch_bounds__(256) mlp_kernel(const float4* __restrict__ ft4,
                                                  const float* __restrict__ coords,
                                                  const float* __restrict__ cell,
                                                  const float* __restrict__ W1,
                                                  const float* __restrict__ b1,
                                                  const float* __restrict__ Wr,
                                                  const float* __restrict__ br,
                                                  const float* __restrict__ W2,
                                                  const float* __restrict__ b2,
                                                  float* __restrict__ prm) {
    __shared__ __align__(16) float act[68 * 128];
    float4* actv4 = (float4*)act;

    const int t = threadIdx.x;
    const int q = t & 15;    // output j-quad: rows 4q..4q+3
    const int pg8 = t >> 4;  // 0..15 -> points 8*pg8..8*pg8+7
    const int blk0 = blockIdx.x * 128;

    // ---- Phase A: anchor bilinear gather (thread: point pt = t&127, quads 2g+hi) ----
    {
        const int pt = t & 127;
        const int hi = t >> 7;
        const int pg = blk0 + pt;
        const int bb = pg >> 14;
        const float gx = coords[2 * pg], gy = coords[2 * pg + 1];
        float ix = clampf((gx + 1.0f) * 0.5f * 255.0f, 0.0f, 255.0f);
        float iy = clampf((gy + 1.0f) * 0.5f * 255.0f, 0.0f, 255.0f);
        float x0f = floorf(ix), y0f = floorf(iy);
        float wx = ix - x0f, wy = iy - y0f;
        int x0 = (int)x0f, y0 = (int)y0f;
        int x1 = min(x0 + 1, 255), y1 = min(y0 + 1, 255);
        const float4* base = ft4 + (size_t)bb * (HH * WW) * 16;
        int i00 = ((y0 << 8) + x0) * 16, i01 = ((y0 << 8) + x1) * 16;
        int i10 = ((y1 << 8) + x0) * 16, i11 = ((y1 << 8) + x1) * 16;
        float w00 = (1.0f - wx) * (1.0f - wy), w01 = wx * (1.0f - wy);
        float w10 = (1.0f - wx) * wy, w11 = wx * wy;
        const int p4 = pt >> 2, plo = pt & 3;
#pragma unroll
        for (int g = 0; g < 8; ++g) {
            int qq = 2 * g + hi;
            float4 f00 = base[i00 + qq], f01 = base[i01 + qq];
            float4 f10 = base[i10 + qq], f11 = base[i11 + qq];
            float vx = f00.x * w00 + f01.x * w01 + f10.x * w10 + f11.x * w11;
            float vy = f00.y * w00 + f01.y * w01 + f10.y * w10 + f11.y * w11;
            float vz = f00.z * w00 + f01.z * w01 + f10.z * w10 + f11.z * w11;
            float vw = f00.w * w00 + f01.w * w01 + f10.w * w10 + f11.w * w11;
            int r0 = 4 * qq;
            act[(r0 + 0) * 128 + ((p4 ^ ((r0 + 0) & 7)) << 2) + plo] = vx;
            act[(r0 + 1) * 128 + ((p4 ^ ((r0 + 1) & 7)) << 2) + plo] = vy;
            act[(r0 + 2) * 128 + ((p4 ^ ((r0 + 2) & 7)) << 2) + plo] = vz;
            act[(r0 + 3) * 128 + ((p4 ^ ((r0 + 3) & 7)) << 2) + plo] = vw;
        }
        if (t < 128) {  // rows 64..67: gx, gy, cx, cy ; (64+e)&7 == e
            act[64 * 128 + ((p4 ^ 0) << 2) + plo] = gx;
            act[65 * 128 + ((p4 ^ 1) << 2) + plo] = gy;
            act[66 * 128 + ((p4 ^ 2) << 2) + plo] = cell[2 * pg];
            act[67 * 128 + ((p4 ^ 3) << 2) + plo] = cell[2 * pg + 1];
        }
    }
    __syncthreads();

    const int s0 = 2 * pg8, s1 = 2 * pg8 + 1;

    // ---- Layer 1: h = leaky(in @ W1 + b1) ----
    float hres[4][8];
    {
        float acc[4][8];
        float4 b4 = ((const float4*)b1)[q];
        float bj[4] = {b4.x, b4.y, b4.z, b4.w};
#pragma unroll
        for (int j = 0; j < 4; ++j)
#pragma unroll
            for (int p = 0; p < 8; ++p) acc[j][p] = bj[j];
        const float4* W14 = (const float4*)W1;
#pragma unroll 4
        for (int i = 0; i < 68; ++i) {
            int sw = i & 7;
            float4 a0 = actv4[i * 32 + (s0 ^ sw)];
            float4 a1 = actv4[i * 32 + (s1 ^ sw)];
            float4 wv = W14[i * 16 + q];
            float a[8] = {a0.x, a0.y, a0.z, a0.w, a1.x, a1.y, a1.z, a1.w};
            float wj[4] = {wv.x, wv.y, wv.z, wv.w};
#pragma unroll
            for (int j = 0; j < 4; ++j)
#pragma unroll
                for (int p = 0; p < 8; ++p) acc[j][p] = fmaf(a[p], wj[j], acc[j][p]);
        }
#pragma unroll
        for (int j = 0; j < 4; ++j)
#pragma unroll
            for (int p = 0; p < 8; ++p) hres[j][p] = leaky_f(acc[j][p]);
    }
    __syncthreads();  // layer-1 input reads complete
#pragma unroll
    for (int j = 0; j < 4; ++j) {
        int r = 4 * q + j, sw = r & 7;
        actv4[r * 32 + (s0 ^ sw)] =
            make_float4(hres[j][0], hres[j][1], hres[j][2], hres[j][3]);
        actv4[r * 32 + (s1 ^ sw)] =
            make_float4(hres[j][4], hres[j][5], hres[j][6], hres[j][7]);
    }
    __syncthreads();

    // ---- Layer 2: h2 = leaky(h + h @ Wr + br) ----
    float h2[4][8];
    {
        float4 b4 = ((const float4*)br)[q];
        float bj[4] = {b4.x, b4.y, b4.z, b4.w};
#pragma unroll
        for (int j = 0; j < 4; ++j)
#pragma unroll
            for (int p = 0; p < 8; ++p) h2[j][p] = bj[j];
        const float4* Wr4 = (const float4*)Wr;
#pragma unroll 4
        for (int i = 0; i < 64; ++i) {
            int sw = i & 7;
            float4 a0 = actv4[i * 32 + (s0 ^ sw)];
            float4 a1 = actv4[i * 32 + (s1 ^ sw)];
            float4 wv = Wr4[i * 16 + q];
            float a[8] = {a0.x, a0.y, a0.z, a0.w, a1.x, a1.y, a1.z, a1.w};
            float wj[4] = {wv.x, wv.y, wv.z, wv.w};
#pragma unroll
            for (int j = 0; j < 4; ++j)
#pragma unroll
                for (int p = 0; p < 8; ++p) h2[j][p] = fmaf(a[p], wj[j], h2[j][p]);
        }
#pragma unroll
        for (int j = 0; j < 4; ++j)
#pragma unroll
            for (int p = 0; p < 8; ++p) h2[j][p] = leaky_f(hres[j][p] + h2[j][p]);
    }
    __syncthreads();  // layer-2 input reads complete
#pragma unroll
    for (int j = 0; j < 4; ++j) {
        int r = 4 * q + j, sw = r & 7;
        actv4[r * 32 + (s0 ^ sw)] = make_float4(h2[j][0], h2[j][1], h2[j][2], h2[j][3]);
        actv4[r * 32 + (s1 ^ sw)] = make_float4(h2[j][4], h2[j][5], h2[j][6], h2[j][7]);
    }
    __syncthreads();

    // ---- Layer 3: out = h2 @ W2 + b2 (29 outputs; thread does j0=2q, j1=2q+1) ----
    float o0[8], o1[8];
    {
        const int j0 = 2 * q, j1 = 2 * q + 1;
        const int jj0 = min(j0, 28), jj1 = min(j1, 28);
        float bb0 = b2[jj0], bb1 = b2[jj1];
#pragma unroll
        for (int p = 0; p < 8; ++p) {
            o0[p] = bb0;
            o1[p] = bb1;
        }
#pragma unroll 4
        for (int i = 0; i < 64; ++i) {
            int sw = i & 7;
            float4 a0 = actv4[i * 32 + (s0 ^ sw)];
            float4 a1 = actv4[i * 32 + (s1 ^ sw)];
            float w0 = W2[i * 29 + jj0], w1 = W2[i * 29 + jj1];
            float a[8] = {a0.x, a0.y, a0.z, a0.w, a1.x, a1.y, a1.z, a1.w};
#pragma unroll
            for (int p = 0; p < 8; ++p) {
                o0[p] = fmaf(a[p], w0, o0[p]);
                o1[p] = fmaf(a[p], w1, o1[p]);
            }
        }
    }
    __syncthreads();  // layer-3 reads complete before sot overlay

    // ---- sot overlay in act memory: sot(pt, j) = act[pt*31 + j] (odd stride: bank spread)
    {
        const int j0 = 2 * q, j1 = 2 * q + 1;
#pragma unroll
        for (int p = 0; p < 8; ++p) {
            int pt = 8 * pg8 + p;
            if (j0 < 29) act[pt * 31 + j0] = o0[p];
            if (j1 < 29) act[pt * 31 + j1] = o1[p];
        }
    }
    __syncthreads();

    // ---- Head: 2 threads/point; sub handles taps k = sub, sub+2, ... ----
    {
        const int pt = t >> 1, sub = t & 1;
        const int pg = blk0 + pt;
        const float* so = act + pt * 31;
        float gx = coords[2 * pg], gy = coords[2 * pg + 1];
        float r = clampf(softplus_f(so[0]) + 0.1f, 0.1f, 4.0f);
        float sg = clampf(softplus_f(so[1]) + 0.5f, 0.5f, 6.0f);
        float se = sg * 2.0f;
        float inv2 = -0.5f / (se * se + 1e-8f);
        float sx[5], sy[5], wv[5];
        float s = 0.0f;
#pragma unroll
        for (int ii = 0; ii < 5; ++ii) {
            int kr = 2 * ii + sub;
            int k = kr < 9 ? kr : 0;
            float bx = (float)(k % 3 - 1);
            float by = (float)(k / 3 - 1);
            float ox = fmaf(r, bx, tanhf(so[2 + 2 * k]) * 0.5f);
            float oy = fmaf(r, by, tanhf(so[3 + 2 * k]) * 0.5f);
            float d2 = ox * ox + oy * oy;
            float wgeo = expf(d2 * inv2);
            float gate = 1.0f / (1.0f + expf(-so[20 + k]));
            float w = (kr < 9) ? wgeo * gate : 0.0f;
            wv[ii] = w;
            s += w;
            sx[ii] = fmaf(ox, SCLX, gx);
            sy[ii] = fmaf(oy, SCLY, gy);
        }
        s += __shfl_xor(s, 1, 64);
        float inv = 1.0f / (s + 1e-8f);
        float* pp = prm + (size_t)pg * PRM_STRIDE;
#pragma unroll
        for (int ii = 0; ii < 5; ++ii) {
            int kr = 2 * ii + sub;
            if (kr < 9) {
                pp[3 * kr + 0] = sx[ii];
                pp[3 * kr + 1] = sy[ii];
                pp[3 * kr + 2] = wv[ii] * inv;
            }
        }
    }
}

// ---------------- K3: deformable gather, thread = (point, channel-quad) ----------------
__global__ void __launch_bounds__(256) gather_kernel(const float4* __restrict__ ft4,
                                                     const float* __restrict__ prm,
                                                     float4* __restrict__ out4) {
    int tid = blockIdx.x * 256 + threadIdx.x;
    int c4 = tid & 15;
    int p = tid >> 4;
    int bb = p >> 14;
    const float4* base = ft4 + (size_t)bb * (HH * WW) * 16;
    const float* pp = prm + (size_t)p * PRM_STRIDE;
    float4 acc = make_float4(0.0f, 0.0f, 0.0f, 0.0f);
#pragma unroll 3
    for (int k = 0; k < K_TAPS; ++k) {
        float sx = pp[3 * k + 0];
        float sy = pp[3 * k + 1];
        float wk = pp[3 * k + 2];
        float4 v = bilin4(base, sx, sy, c4);
        acc.x = fmaf(v.x, wk, acc.x);
        acc.y = fmaf(v.y, wk, acc.y);
        acc.z = fmaf(v.z, wk, acc.z);
        acc.w = fmaf(v.w, wk, acc.w);
    }
    out4[(size_t)p * 16 + c4] = acc;
}

// ---------------- small fallback: CHW, wave per point (no workspace) ----------------
__device__ __forceinline__ float bilin_chw(const float* __restrict__ feat, int b, int lane,
                                           float gx, float gy) {
    float ix = clampf((gx + 1.0f) * 0.5f * 255.0f, 0.0f, 255.0f);
    float iy = clampf((gy + 1.0f) * 0.5f * 255.0f, 0.0f, 255.0f);
    float x0f = floorf(ix), y0f = floorf(iy);
    float wx = ix - x0f, wy = iy - y0f;
    int x0 = (int)x0f, y0 = (int)y0f;
    int x1 = min(x0 + 1, 255), y1 = min(y0 + 1, 255);
    const float* base = feat + ((size_t)b * CC + lane) * (HH * WW);
    float f00 = base[(y0 << 8) + x0];
    float f01 = base[(y0 << 8) + x1];
    float f10 = base[(y1 << 8) + x0];
    float f11 = base[(y1 << 8) + x1];
    float omx = 1.0f - wx, omy = 1.0f - wy;
    return (f00 * omx + f01 * wx) * omy + (f10 * omx + f11 * wx) * wy;
}

__global__ void __launch_bounds__(256) fallback_kernel(const float* __restrict__ feat,
                                                       const float* __restrict__ coords,
                                                       const float* __restrict__ cell,
                                                       const float* __restrict__ W1,
                                                       const float* __restrict__ b1,
                                                       const float* __restrict__ Wr,
                                                       const float* __restrict__ br,
                                                       const float* __restrict__ W2,
                                                       const float* __restrict__ b2,
                                                       float* __restrict__ out) {
    int lane = threadIdx.x & 63;
    int wave = threadIdx.x >> 6;
    int pidx = blockIdx.x * 4 + wave;
    if (pidx >= NPTS) return;
    int b = pidx >> 14;
    float gx = coords[(size_t)pidx * 2 + 0];
    float gy = coords[(size_t)pidx * 2 + 1];
    float cx = cell[(size_t)pidx * 2 + 0];
    float cy = cell[(size_t)pidx * 2 + 1];
    float fa = bilin_chw(feat, b, lane, gx, gy);
    float h = b1[lane];
#pragma unroll
    for (int i = 0; i < 64; ++i) {
        float a = __shfl(fa, i, 64);
        h = fmaf(a, W1[i * 64 + lane], h);
    }
    h = fmaf(gx, W1[64 * 64 + lane], h);
    h = fmaf(gy, W1[65 * 64 + lane], h);
    h = fmaf(cx, W1[66 * 64 + lane], h);
    h = fmaf(cy, W1[67 * 64 + lane], h);
    h = leaky_f(h);
    float h2 = br[lane];
#pragma unroll
    for (int i = 0; i < 64; ++i) {
        float a = __shfl(h, i, 64);
        h2 = fmaf(a, Wr[i * 64 + lane], h2);
    }
    h2 = leaky_f(h + h2);
    int j = lane < 29 ? lane : 0;
    float o = b2[j];
#pragma unroll
    for (int i = 0; i < 64; ++i) {
        float a = __shfl(h2, i, 64);
        o = fmaf(a, W2[i * 29 + j], o);
    }
    int kk = lane < K_TAPS ? lane : 0;
    float r_raw = __shfl(o, 0, 64);
    float s_raw = __shfl(o, 1, 64);
    float rx_raw = __shfl(o, 2 + 2 * kk, 64);
    float ry_raw = __shfl(o, 3 + 2 * kk, 64);
    float g_raw = __shfl(o, 20 + kk, 64);
    float r = clampf(softplus_f(r_raw) + 0.1f, 0.1f, 4.0f);
    float sg = clampf(softplus_f(s_raw) + 0.5f, 0.5f, 6.0f);
    float bx = (float)(kk % 3 - 1);
    float by = (float)(kk / 3 - 1);
    float offx = fmaf(r, bx, tanhf(rx_raw) * 0.5f);
    float offy = fmaf(r, by, tanhf(ry_raw) * 0.5f);
    float d2 = offx * offx + offy * offy;
    float se = sg * 2.0f;
    float wgeo = expf(-0.5f * d2 / (se * se + 1e-8f));
    float gate = 1.0f / (1.0f + expf(-g_raw));
    float w = wgeo * gate;
    float wv = (lane < K_TAPS) ? w : 0.0f;
#pragma unroll
    for (int m = 32; m >= 1; m >>= 1) wv += __shfl_xor(wv, m, 64);
    float wn = w / (wv + 1e-8f);
    float acc = 0.0f;
#pragma unroll
    for (int k = 0; k < K_TAPS; ++k) {
        float ox = __shfl(offx, k, 64) * SCLX;
        float oy = __shfl(offy, k, 64) * SCLY;
        float wk2 = __shfl(wn, k, 64);
        float fv = bilin_chw(feat, b, lane, gx + ox, gy + oy);
        acc = fmaf(fv, wk2, acc);
    }
    out[(size_t)pidx * CC + lane] = acc;
}

extern "C" void kernel_launch(void* const* d_in, const int* in_sizes, int n_in,
                              void* d_out, int out_size, void* d_ws, size_t ws_size,
                              hipStream_t stream) {
    const float* feat = (const float*)d_in[0];
    const float* coords = (const float*)d_in[1];
    const float* cell = (const float*)d_in[2];
    const float* W1 = (const float*)d_in[3];
    const float* b1 = (const float*)d_in[4];
    const float* Wr = (const float*)d_in[5];
    const float* br = (const float*)d_in[6];
    const float* W2 = (const float*)d_in[7];
    const float* b2 = (const float*)d_in[8];
    float* out = (float*)d_out;

    const size_t needT = (size_t)BB * HH * WW * CC * sizeof(float);  // 64 MB
    const size_t needP = (size_t)NPTS * PRM_STRIDE * sizeof(float);  // 8 MB

    if (ws_size >= needT + needP) {
        float* featT = (float*)d_ws;
        float* prm = (float*)((char*)d_ws + needT);
        dim3 tg((HH * WW) / 64, BB);
        transpose_kernel<<<tg, 256, 0, stream>>>(feat, featT);
        mlp_kernel<<<NPTS / 128, 256, 0, stream>>>((const float4*)featT, coords, cell, W1, b1,
                                                   Wr, br, W2, b2, prm);
        gather_kernel<<<(NPTS * 16) / 256, 256, 0, stream>>>((const float4*)featT, prm,
                                                             (float4*)out);
    } else {
        fallback_kernel<<<NPTS / 4, 256, 0, stream>>>(feat, coords, cell, W1, b1, Wr, br, W2,
                                                      b2, out);
    }
}